// Round 3
// baseline (454.478 us; speedup 1.0000x reference)
//
#include <hip/hip_runtime.h>
#include <hip/hip_bf16.h>
#include <math.h>

#define N_SEQ 4096
#define D_MODEL 1024
#define CAND_CAP 512

typedef __attribute__((ext_vector_type(8))) short short8;
typedef __attribute__((ext_vector_type(4))) float f32x4;

__device__ __forceinline__ short f2bf(float f) {
  __hip_bfloat16 h = __float2bfloat16(f);
  return *reinterpret_cast<short*>(&h);
}
__device__ __forceinline__ float bf2f(short h) {
  return __uint_as_float(((unsigned)(unsigned short)h) << 16);
}

// async global->LDS, 16B per lane. LDS dest must be wave-uniform base + lane*16.
__device__ __forceinline__ void gload16(const short* g, short* l) {
  __builtin_amdgcn_global_load_lds(
      (const __attribute__((address_space(1))) void*)g,
      (__attribute__((address_space(3))) void*)l, 16, 0, 0);
}

// ---------------------------------------------------------------------------
// XOR-swizzled staging (NT thr): tile ROWS x 64 shorts. Slot s (16B):
// r = s>>3, c8 = (s&7)^(r&7) -> fragment ds_read_b128 hits all 32 banks
// (2-way, free — verified R4: conflicts 6.5e6 -> 0). HL: row = [hi 32 | lo 32].
// ---------------------------------------------------------------------------
template <int ROWS, bool HL, int NT>
__device__ __forceinline__ void stage_sw(const short* __restrict__ hi,
                                         const short* __restrict__ lo, int ld,
                                         int r0, int k0, short* dst, int tid) {
#pragma unroll
  for (int i = 0; i < ROWS * 8 / NT; ++i) {
    const int s = i * NT + tid;
    const int r = s >> 3;
    const int c8 = (s & 7) ^ (r & 7);
    const short* src;
    int col;
    if (HL) {
      src = (c8 < 4) ? hi : lo;
      col = (c8 & 3) * 8;
    } else {
      src = hi;
      col = c8 * 8;
    }
    gload16(&src[(size_t)(r0 + r) * ld + k0 + col], &dst[s * 8]);
  }
}

// HL inner step (KSTEP=32): MI x NIv wave tile, 3-product split-bf16.
template <int MI, int NIv>
__device__ __forceinline__ void hl_step(const short* sA, const short* sB,
                                        int wm, int wn, int quad, int l15,
                                        f32x4 acc[MI][NIv]) {
  short8 a[MI], am[MI], b[NIv], bm[NIv];
#pragma unroll
  for (int mi = 0; mi < MI; ++mi) {
    const int rr = wm + mi * 16 + l15;
    a[mi] = *(const short8*)&sA[rr * 64 + ((quad ^ (rr & 7)) << 3)];
    am[mi] = *(const short8*)&sA[rr * 64 + (((quad + 4) ^ (rr & 7)) << 3)];
  }
#pragma unroll
  for (int ni = 0; ni < NIv; ++ni) {
    const int rr = wn + ni * 16 + l15;
    b[ni] = *(const short8*)&sB[rr * 64 + ((quad ^ (rr & 7)) << 3)];
    bm[ni] = *(const short8*)&sB[rr * 64 + (((quad + 4) ^ (rr & 7)) << 3)];
  }
#pragma unroll
  for (int mi = 0; mi < MI; ++mi)
#pragma unroll
    for (int ni = 0; ni < NIv; ++ni) {
      acc[mi][ni] = __builtin_amdgcn_mfma_f32_16x16x32_bf16(a[mi], b[ni],
                                                            acc[mi][ni], 0, 0, 0);
      acc[mi][ni] = __builtin_amdgcn_mfma_f32_16x16x32_bf16(a[mi], bm[ni],
                                                            acc[mi][ni], 0, 0, 0);
      acc[mi][ni] = __builtin_amdgcn_mfma_f32_16x16x32_bf16(am[mi], b[ni],
                                                            acc[mi][ni], 0, 0, 0);
    }
}

// non-HL inner step (KSTEP=64): two k=32 slices.
template <int MI, int NIv>
__device__ __forceinline__ void bf_step(const short* sA, const short* sB,
                                        int wm, int wn, int quad, int l15,
                                        f32x4 acc[MI][NIv]) {
#pragma unroll
  for (int s = 0; s < 2; ++s) {
    short8 a[MI], b[NIv];
#pragma unroll
    for (int mi = 0; mi < MI; ++mi) {
      const int rr = wm + mi * 16 + l15;
      a[mi] = *(const short8*)&sA[rr * 64 + (((s * 4 + quad) ^ (rr & 7)) << 3)];
    }
#pragma unroll
    for (int ni = 0; ni < NIv; ++ni) {
      const int rr = wn + ni * 16 + l15;
      b[ni] = *(const short8*)&sB[rr * 64 + (((s * 4 + quad) ^ (rr & 7)) << 3)];
    }
#pragma unroll
    for (int mi = 0; mi < MI; ++mi)
#pragma unroll
      for (int ni = 0; ni < NIv; ++ni)
        acc[mi][ni] = __builtin_amdgcn_mfma_f32_16x16x32_bf16(
            a[mi], b[ni], acc[mi][ni], 0, 0, 0);
  }
}

// ---------------------------------------------------------------------------
// qproj: q = x @ wqk, HL 3-product (q must be fp32-grade: refinement +
// scores build on it). R12: split-K x2 — 1024 blocks x 256 thr, 128x64
// tiles, uniform nk=16, 4 blocks/CU (R10's co-residency lever; old 512-block
// grid = 2/CU left stage latency half-exposed: 41.6 us @ 620 TF).
// Partners b and b+512 (same CU under round-robin) write disjoint f32
// partial buffers (plain stores); per-tile counter elects the SECOND
// arriver as finisher: sums own in-register partial + partner's stored
// partial -> qh (bf16) + qf (f32, exact — replaces the old ql split).
// Release: threadfence+syncthreads then acq_rel agent atomicAdd; acquire:
// fence before partner reads. Correct under any scheduling (G16).
// ---------------------------------------------------------------------------
__global__ __launch_bounds__(256, 4)
void qproj(const short* __restrict__ xh, const short* __restrict__ xl,
           const short* __restrict__ wqkTh, const short* __restrict__ wqkTl,
           float* __restrict__ qpart, short* __restrict__ qh,
           float* __restrict__ qf, int* __restrict__ cnt) {
  __shared__ short sA[128 * 64];
  __shared__ short sB[64 * 64];
  __shared__ int sfin;
  const int tid = threadIdx.x;
  const int w = tid >> 6, lane = tid & 63;
  const int quad = lane >> 4, l15 = lane & 15;
  const int wm = (w >> 1) * 64, wn = (w & 1) * 32;

  const int b = blockIdx.x;
  const int tile = b & 511;  // partners b and b+512 -> same CU (heuristic)
  const int h = b >> 9;      // K-half
  const int mt = tile >> 4, nt = tile & 15;  // 32 x 16 tile grid
  const int m0 = mt * 128, n0 = nt * 64;
  const int kb = h * 512;

  f32x4 acc[4][2];
#pragma unroll
  for (int mi = 0; mi < 4; ++mi)
#pragma unroll
    for (int ni = 0; ni < 2; ++ni)
#pragma unroll
      for (int r = 0; r < 4; ++r) acc[mi][ni][r] = 0.f;

  for (int kt = 0; kt < 16; ++kt) {
    const int k0 = kb + kt * 32;
    stage_sw<128, true, 256>(xh, xl, 1024, m0, k0, sA, tid);
    stage_sw<64, true, 256>(wqkTh, wqkTl, 1024, n0, k0, sB, tid);
    __syncthreads();
    hl_step<4, 2>(sA, sB, wm, wn, quad, l15, acc);
    __syncthreads();
  }

  // store own partial (plain f32, coalesced over l15)
  float* myp = qpart + (size_t)h * (N_SEQ * (size_t)D_MODEL);
#pragma unroll
  for (int mi = 0; mi < 4; ++mi)
#pragma unroll
    for (int ni = 0; ni < 2; ++ni)
#pragma unroll
      for (int r = 0; r < 4; ++r) {
        const int row = m0 + wm + mi * 16 + quad * 4 + r;
        const int col = n0 + wn + ni * 16 + l15;
        myp[(size_t)row * D_MODEL + col] = acc[mi][ni][r];
      }

  // release own stores, elect finisher
  __threadfence();
  __syncthreads();
  if (tid == 0)
    sfin = __hip_atomic_fetch_add(&cnt[tile], 1, __ATOMIC_ACQ_REL,
                                  __HIP_MEMORY_SCOPE_AGENT);
  __syncthreads();
  if (sfin == 1) {
    __threadfence();  // acquire: partner's partial now visible
    const float* op = qpart + (size_t)(1 - h) * (N_SEQ * (size_t)D_MODEL);
#pragma unroll
    for (int mi = 0; mi < 4; ++mi)
#pragma unroll
      for (int ni = 0; ni < 2; ++ni)
#pragma unroll
        for (int r = 0; r < 4; ++r) {
          const int row = m0 + wm + mi * 16 + quad * 4 + r;
          const int col = n0 + wn + ni * 16 + l15;
          const float s = acc[mi][ni][r] + op[(size_t)row * D_MODEL + col];
          qh[(size_t)row * D_MODEL + col] = f2bf(s);
          qf[(size_t)row * D_MODEL + col] = s;
        }
  }
}

// ---------------------------------------------------------------------------
// Fused QK + vT dispatch, 784 blocks x 256 thr (4 waves, 64x64 wave tiles):
//  blocks [0,528): S~ = qh @ xh^T causal (supertile-8, 1-PRODUCT bf16 —
//    estimate only, stored bf16; total error |s~-s| <~ 26 incl. quant,
//    refined exactly in softmax for entries within 64 of the row max)
//  blocks [528,784): vT = (x @ wov)^T rect NT GEMM (bf16, ldc 4096)
// All blocks ~equal length (16 K-iters) — uniform 3 blocks/CU.
// ---------------------------------------------------------------------------
__global__ __launch_bounds__(256, 2)
void fused_qk_v(const short* __restrict__ qh, const short* __restrict__ xh,
                const short* __restrict__ wovT, short* __restrict__ S,
                short* __restrict__ vT) {
  __shared__ short sA[128 * 64];
  __shared__ short sB[128 * 64];
  const int tid = threadIdx.x;
  const int w = tid >> 6, lane = tid & 63;
  const int quad = lane >> 4, l15 = lane & 15;
  const int wm = (w >> 1) * 64, wn = (w & 1) * 64;

  f32x4 acc[4][4];
#pragma unroll
  for (int mi = 0; mi < 4; ++mi)
#pragma unroll
    for (int ni = 0; ni < 4; ++ni)
#pragma unroll
      for (int r = 0; r < 4; ++r) acc[mi][ni][r] = 0.f;

  if (blockIdx.x < 528) {
    // ---- QK causal estimate, supertile-8 decode ----
    const int f = blockIdx.x;
    int R;
    if (f < 36) R = 0;
    else if (f < 136) R = 1;
    else if (f < 300) R = 2;
    else R = 3;
    const int rem = f - (32 * R * R + 4 * R);
    const int full = R << 6;
    int mt, nt;
    if (rem < full) {
      const int C = rem >> 6, ww = rem & 63;
      mt = 8 * R + (ww >> 3);
      nt = 8 * C + (ww & 7);
    } else {
      const int d = rem - full;
      int lm = 0;
      while ((lm + 1) * (lm + 2) / 2 <= d) ++lm;
      mt = 8 * R + lm;
      nt = 8 * R + d - lm * (lm + 1) / 2;
    }
    const int m0 = mt * 128, n0 = nt * 128;
    for (int kt = 0; kt < 16; ++kt) {
      const int k0 = kt * 64;
      stage_sw<128, false, 256>(qh, nullptr, 1024, m0, k0, sA, tid);
      stage_sw<128, false, 256>(xh, nullptr, 1024, n0, k0, sB, tid);
      __syncthreads();
      bf_step<4, 4>(sA, sB, wm, wn, quad, l15, acc);
      __syncthreads();
    }
#pragma unroll
    for (int mi = 0; mi < 4; ++mi)
#pragma unroll
      for (int ni = 0; ni < 4; ++ni)
#pragma unroll
        for (int r = 0; r < 4; ++r) {
          const int row = m0 + wm + mi * 16 + quad * 4 + r;
          const int col = n0 + wn + ni * 16 + l15;
          S[(size_t)row * N_SEQ + col] = f2bf(acc[mi][ni][r]);
        }
  } else {
    // ---- vT = (x @ wov)^T : C[m][n] = sum_d wovT[m][d] * xh[n][d] ----
    const int f2 = blockIdx.x - 528;
    const int mt = f2 >> 5, nt = f2 & 31;
    const int m0 = mt * 128, n0 = nt * 128;
    for (int kt = 0; kt < 16; ++kt) {
      const int k0 = kt * 64;
      stage_sw<128, false, 256>(wovT, nullptr, 1024, m0, k0, sA, tid);
      stage_sw<128, false, 256>(xh, nullptr, 1024, n0, k0, sB, tid);
      __syncthreads();
      bf_step<4, 4>(sA, sB, wm, wn, quad, l15, acc);
      __syncthreads();
    }
#pragma unroll
    for (int mi = 0; mi < 4; ++mi)
#pragma unroll
      for (int ni = 0; ni < 4; ++ni)
#pragma unroll
        for (int r = 0; r < 4; ++r) {
          const int row = m0 + wm + mi * 16 + quad * 4 + r;
          const int col = n0 + wn + ni * 16 + l15;
          vT[(size_t)row * N_SEQ + col] = f2bf(acc[mi][ni][r]);
        }
  }
}

// ---------------------------------------------------------------------------
// Softmax + sparse exact refinement, one block (256 thr) per row, in place.
// S~ bf16 (threshold 64 covers est+quant error ~26; unrefined true weight
// <= e^-12 — negligible). Row cache fv[2][8] statically indexed (rule #20).
// Candidates refined wave-parallel; exact fp32 q row read from qf (R12:
// replaces qh+ql reconstruction). Exact row max = max(refv) since any
// unrefined entry < thr < best candidate.
// ---------------------------------------------------------------------------
__global__ __launch_bounds__(256)
void softmax_refine(short* __restrict__ S, const float* __restrict__ qfg,
                    const short* __restrict__ xh, const short* __restrict__ xl) {
  const int gi = blockIdx.x;
  const int valid = gi + 1;
  const int padded = ((gi >> 7) + 1) << 7;
  const int nf8 = padded >> 3;
  short* srow = S + (size_t)gi * N_SEQ;
  const int tid = threadIdx.x;
  const int w = tid >> 6, lane = tid & 63;
  __shared__ float wred[4];
  __shared__ float sm, sil;
  __shared__ __align__(16) float qf[D_MODEL];
  __shared__ int cand[CAND_CAP];
  __shared__ float refv[CAND_CAP];
  __shared__ int ccnt;

  // load row (bf16 -> f32 regs, static layout) + estimate max
  float fv[2][8];
  float m = -1e30f;
#pragma unroll
  for (int k = 0; k < 2; ++k) {
    const int j8 = tid + (k << 8);
    if (j8 < nf8) {
      const short8 h = ((const short8*)srow)[j8];
#pragma unroll
      for (int e = 0; e < 8; ++e) {
        fv[k][e] = bf2f(h[e]);
        if ((j8 << 3) + e < valid) m = fmaxf(m, fv[k][e]);
      }
    }
  }
#pragma unroll
  for (int off = 32; off > 0; off >>= 1) m = fmaxf(m, __shfl_down(m, off));
  if (lane == 0) wred[w] = m;
  // exact fp32 q row -> LDS (one float4 per thread: D/4 == 256)
  {
    const float4 qv = ((const float4*)(qfg + (size_t)gi * D_MODEL))[tid];
    qf[tid * 4 + 0] = qv.x;
    qf[tid * 4 + 1] = qv.y;
    qf[tid * 4 + 2] = qv.z;
    qf[tid * 4 + 3] = qv.w;
  }
  if (tid == 0) ccnt = 0;
  __syncthreads();
  if (tid == 0) sm = fmaxf(fmaxf(wred[0], wred[1]), fmaxf(wred[2], wred[3]));
  __syncthreads();

  // collect candidates
  const float thr = sm - 64.0f;
#pragma unroll
  for (int k = 0; k < 2; ++k) {
    const int j8 = tid + (k << 8);
    if (j8 < nf8) {
#pragma unroll
      for (int e = 0; e < 8; ++e) {
        const int j = (j8 << 3) + e;
        if (j < valid && fv[k][e] > thr) {
          const int ix = atomicAdd(&ccnt, 1);
          if (ix < CAND_CAP) cand[ix] = j;
        }
      }
    }
  }
  __syncthreads();
  const int nc = min(ccnt, CAND_CAP);

  // exact fp32 dot per candidate — one wave per candidate, vectorized loads
  for (int c = w; c < nc; c += 4) {
    const int j = cand[c];
    const short4* xhr = (const short4*)(xh + (size_t)j * D_MODEL);
    const short4* xlr = (const short4*)(xl + (size_t)j * D_MODEL);
    float part = 0.f;
#pragma unroll
    for (int s = 0; s < 4; ++s) {
      const int d4 = lane + (s << 6);
      const short4 hx = xhr[d4];
      const short4 lx = xlr[d4];
      const float4 qv = *(const float4*)&qf[d4 << 2];
      part += qv.x * (bf2f(hx.x) + bf2f(lx.x));
      part += qv.y * (bf2f(hx.y) + bf2f(lx.y));
      part += qv.z * (bf2f(hx.z) + bf2f(lx.z));
      part += qv.w * (bf2f(hx.w) + bf2f(lx.w));
    }
#pragma unroll
    for (int off = 32; off > 0; off >>= 1) part += __shfl_down(part, off);
    if (lane == 0) refv[c] = part;
  }
  __syncthreads();

  // exact row max = max over refined candidates (unrefined < thr < this)
  m = -1e30f;
  for (int c = 0; c < nc; ++c) m = fmaxf(m, refv[c]);

  // patch register copies — static indexing, scan the candidate list
#pragma unroll
  for (int k = 0; k < 2; ++k) {
    const int j8 = tid + (k << 8);
    if (j8 < nf8) {
#pragma unroll
      for (int e = 0; e < 8; ++e) {
        const int j = (j8 << 3) + e;
        float x = fv[k][e];
        for (int c = 0; c < nc; ++c)
          if (cand[c] == j) x = refv[c];
        fv[k][e] = x;
      }
    }
  }

  // sum
  float l = 0.f;
#pragma unroll
  for (int k = 0; k < 2; ++k) {
    const int j8 = tid + (k << 8);
    if (j8 < nf8) {
#pragma unroll
      for (int e = 0; e < 8; ++e) {
        const float p = ((j8 << 3) + e < valid) ? __expf(fv[k][e] - m) : 0.f;
        fv[k][e] = p;
        l += p;
      }
    }
  }
#pragma unroll
  for (int off = 32; off > 0; off >>= 1) l += __shfl_down(l, off);
  if (lane == 0) wred[w] = l;
  __syncthreads();
  if (tid == 0) sil = 1.f / (wred[0] + wred[1] + wred[2] + wred[3]);
  __syncthreads();
  const float il = sil;

  // write P bf16 in place (padding cols [valid,padded) get exact 0)
#pragma unroll
  for (int k = 0; k < 2; ++k) {
    const int j8 = tid + (k << 8);
    if (j8 < nf8) {
      short8 o;
#pragma unroll
      for (int e = 0; e < 8; ++e) o[e] = f2bf(fv[k][e] * il);
      ((short8*)srow)[j8] = o;
    }
  }
}

// ---------------------------------------------------------------------------
// PV: out = P @ v. Split-K x2 — 1024 blocks x 256 thr (4 waves, 64x32 wave
// tiles), each block one half-K chunk of a 128x64 tile, nk = mt+1 <= 32.
// Rank map gives every CU chunk sizes {v,33-v,w,33-w} (exactly 66 steps/CU)
// all co-resident (24 KB LDS -> 4 blocks/CU) -> 4-way overlap hides per-step
// latency. Epilogue: fp32 atomicAdd (exactly 2 commutative contributions per
// element); out zeroed in prep_all. A = P (bf16, lda 4096), B = vT (ldb 4096).
// ---------------------------------------------------------------------------
__global__ __launch_bounds__(256, 4)
void pv_gemm(const short* __restrict__ P, const short* __restrict__ vT,
             float* __restrict__ out) {
  __shared__ short sA[128 * 64];
  __shared__ short sB[64 * 64];
  const int tid = threadIdx.x;
  const int w = tid >> 6, lane = tid & 63;
  const int quad = lane >> 4, l15 = lane & 15;
  const int wm = (w >> 1) * 64, wn = (w & 1) * 32;

  // CU c hosts blocks {c, c+256, c+512, c+768} -> ranks {c, 511-c, 512+c,
  // 1023-c} -> nk {v, 33-v, w, 33-w}.
  const int b = blockIdx.x;
  int rk;
  if (b < 256) rk = b;
  else if (b < 512) rk = 767 - b;
  else if (b < 768) rk = b;
  else rk = 1791 - b;
  const int mt = 31 - (rk >> 5);   // rank desc by chunk size
  const int nt = (rk >> 1) & 15;
  const int h = rk & 1;            // which K-half
  const int m0 = mt * 128, n0 = nt * 64;
  const int nk = mt + 1;           // K-steps in this half (K_total = 2*nk*64)
  const int kbase = h * nk * 64;

  f32x4 acc[4][2];
#pragma unroll
  for (int mi = 0; mi < 4; ++mi)
#pragma unroll
    for (int ni = 0; ni < 2; ++ni)
#pragma unroll
      for (int r = 0; r < 4; ++r) acc[mi][ni][r] = 0.f;

  for (int kt = 0; kt < nk; ++kt) {
    const int k0 = kbase + kt * 64;
    stage_sw<128, false, 256>(P, nullptr, 4096, m0, k0, sA, tid);
    stage_sw<64, false, 256>(vT, nullptr, N_SEQ, n0, k0, sB, tid);
    __syncthreads();
    bf_step<4, 2>(sA, sB, wm, wn, quad, l15, acc);
    __syncthreads();
  }
#pragma unroll
  for (int mi = 0; mi < 4; ++mi)
#pragma unroll
    for (int ni = 0; ni < 2; ++ni)
#pragma unroll
      for (int r = 0; r < 4; ++r) {
        const int row = m0 + wm + mi * 16 + quad * 4 + r;
        const int col = n0 + wn + ni * 16 + l15;
        atomicAdd(&out[(size_t)row * D_MODEL + col], acc[mi][ni][r]);
      }
}

// ---------------------------------------------------------------------------
// Fused prep, flat grid of 4608 x 256 thr:
//  b < 4096: x elementwise split -> xh, xl ; also zero out (pv accumulates);
//            b==0 additionally zeroes the 512 qproj tile counters
//  b < 4352: wqk 64x64 tile -> wqkTh, wqkTl (transposed, hi+lo)
//  else    : wov tile -> wovT (transposed)
// ---------------------------------------------------------------------------
__global__ __launch_bounds__(256)
void prep_all(const float* __restrict__ x, const float* __restrict__ wqk,
              const float* __restrict__ wov, short* __restrict__ xh,
              short* __restrict__ xl, short* __restrict__ wqkTh,
              short* __restrict__ wqkTl, short* __restrict__ wovT,
              float* __restrict__ outz, int* __restrict__ cnt) {
  __shared__ short Th[64][72];
  __shared__ short Tl[64][72];
  const int tid = threadIdx.x;
  const int b = blockIdx.x;

  if (b < 4096) {
    if (b == 0) {  // zero qproj tile counters (512 ints)
      cnt[tid] = 0;
      cnt[tid + 256] = 0;
    }
    const int idx = b * 256 + tid;
    const float4 v = ((const float4*)x)[idx];
    const float f[4] = {v.x, v.y, v.z, v.w};
    short h[4], l[4];
#pragma unroll
    for (int i = 0; i < 4; ++i) {
      h[i] = f2bf(f[i]);
      l[i] = f2bf(f[i] - bf2f(h[i]));
    }
    ((short4*)xh)[idx] = make_short4(h[0], h[1], h[2], h[3]);
    ((short4*)xl)[idx] = make_short4(l[0], l[1], l[2], l[3]);
    // zero the output accumulator (same 4096x1024 f32 geometry as x)
    ((float4*)outz)[idx] = make_float4(0.f, 0.f, 0.f, 0.f);
    return;
  }

  const bool is_qk = (b < 4352);
  const int local = b - (is_qk ? 4096 : 4352);
  const float* in = is_qk ? wqk : wov;
  short* hiT = is_qk ? wqkTh : wovT;
  short* loT = is_qk ? wqkTl : nullptr;
  const int r0 = (local & 15) * 64, c0 = (local >> 4) * 64;

#pragma unroll
  for (int i = 0; i < 4; ++i) {
    const int rr = (tid >> 4) + i * 16;
    const int cc = (tid & 15) * 4;
    const float4 v = *(const float4*)&in[(size_t)(r0 + rr) * D_MODEL + c0 + cc];
    const float f[4] = {v.x, v.y, v.z, v.w};
#pragma unroll
    for (int j = 0; j < 4; ++j) {
      const short h = f2bf(f[j]);
      Th[rr][cc + j] = h;
      Tl[rr][cc + j] = is_qk ? f2bf(f[j] - bf2f(h)) : (short)0;
    }
  }
  __syncthreads();
#pragma unroll
  for (int i = 0; i < 2; ++i) {
    const int idx = tid + i * 256;
    const int oc = idx >> 3;
    const int ch = (idx & 7) * 8;
    float4 u;
    short* t = (short*)&u;
#pragma unroll
    for (int j = 0; j < 8; ++j) t[j] = Th[ch + j][oc];
    *(float4*)&hiT[(size_t)(c0 + oc) * D_MODEL + r0 + ch] = u;
    if (loT) {
#pragma unroll
      for (int j = 0; j < 8; ++j) t[j] = Tl[ch + j][oc];
      *(float4*)&loT[(size_t)(c0 + oc) * D_MODEL + r0 + ch] = u;
    }
  }
}

// ---------------------------------------------------------------------------
extern "C" void kernel_launch(void* const* d_in, const int* in_sizes, int n_in,
                              void* d_out, int out_size, void* d_ws,
                              size_t ws_size, hipStream_t stream) {
  (void)in_sizes; (void)n_in; (void)out_size; (void)ws_size;
  const float* x   = (const float*)d_in[0];
  const float* wqk = (const float*)d_in[1];
  const float* wov = (const float*)d_in[2];
  float* out = (float*)d_out;

  const size_t MB = 1ull << 20;
  char* p = (char*)d_ws;
  short* xh    = (short*)(p);             //  8 MB 4096x1024 bf16 hi
  short* xl    = (short*)(p + 8 * MB);    //  8 MB           bf16 lo
  short* wqkTh = (short*)(p + 16 * MB);   //  2 MB
  short* wqkTl = (short*)(p + 18 * MB);   //  2 MB
  short* wovT  = (short*)(p + 20 * MB);   //  2 MB
  short* qh    = (short*)(p + 22 * MB);   //  8 MB 4096x1024 bf16 q hi
  short* vT    = (short*)(p + 30 * MB);   //  8 MB 1024x4096: vT[d][s]=(x@wov)[s][d]
  short* S     = (short*)(p + 38 * MB);   // 32 MB 4096x4096 bf16 S~ (P aliases)
  float* qpart = (float*)(p + 70 * MB);   // 32 MB [2][4096][1024] f32 K-half partials
  float* qf    = (float*)(p + 102 * MB);  // 16 MB 4096x1024 f32 exact q
  int*   cnt   = (int*)(p + 118 * MB);    //  4 KB 512 tile counters
                                          // total ~118 MB

  prep_all<<<4608, 256, 0, stream>>>(x, wqk, wov, xh, xl, wqkTh, wqkTl, wovT,
                                     out, cnt);
  // q = x @ wqk  (split-bf16 3-product, split-K x2, finisher writes qh+qf)
  qproj<<<1024, 256, 0, stream>>>(xh, xl, wqkTh, wqkTl, qpart, qh, qf, cnt);
  // fused: S~ = qh @ xh^T causal 1-product estimate (bf16) + vT = (x@wov)^T
  fused_qk_v<<<784, 256, 0, stream>>>(qh, xh, wovT, S, vT);
  // softmax with sparse exact refinement (exact q from qf) -> P bf16 in place
  softmax_refine<<<N_SEQ, 256, 0, stream>>>(S, qf, xh, xl);
  // out += P @ v  (split-K x2, per-CU balanced, 4-way co-residency)
  pv_gemm<<<1024, 256, 0, stream>>>((const short*)S, vT, out);
}

// Round 4
// 228.430 us; speedup vs baseline: 1.9896x; 1.9896x over previous
//
#include <hip/hip_runtime.h>
#include <hip/hip_bf16.h>
#include <math.h>

#define N_SEQ 4096
#define D_MODEL 1024
#define CAND_CAP 512

typedef __attribute__((ext_vector_type(8))) short short8;
typedef __attribute__((ext_vector_type(4))) float f32x4;

__device__ __forceinline__ short f2bf(float f) {
  __hip_bfloat16 h = __float2bfloat16(f);
  return *reinterpret_cast<short*>(&h);
}
__device__ __forceinline__ float bf2f(short h) {
  return __uint_as_float(((unsigned)(unsigned short)h) << 16);
}

// async global->LDS, 16B per lane. LDS dest must be wave-uniform base + lane*16.
__device__ __forceinline__ void gload16(const short* g, short* l) {
  __builtin_amdgcn_global_load_lds(
      (const __attribute__((address_space(1))) void*)g,
      (__attribute__((address_space(3))) void*)l, 16, 0, 0);
}

// ---------------------------------------------------------------------------
// XOR-swizzled staging (NT thr): tile ROWS x 64 shorts. Slot s (16B):
// r = s>>3, c8 = (s&7)^(r&7) -> fragment ds_read_b128 hits all 32 banks
// (2-way, free — verified R4: conflicts 6.5e6 -> 0). HL: row = [hi 32 | lo 32].
// ---------------------------------------------------------------------------
template <int ROWS, bool HL, int NT>
__device__ __forceinline__ void stage_sw(const short* __restrict__ hi,
                                         const short* __restrict__ lo, int ld,
                                         int r0, int k0, short* dst, int tid) {
#pragma unroll
  for (int i = 0; i < ROWS * 8 / NT; ++i) {
    const int s = i * NT + tid;
    const int r = s >> 3;
    const int c8 = (s & 7) ^ (r & 7);
    const short* src;
    int col;
    if (HL) {
      src = (c8 < 4) ? hi : lo;
      col = (c8 & 3) * 8;
    } else {
      src = hi;
      col = c8 * 8;
    }
    gload16(&src[(size_t)(r0 + r) * ld + k0 + col], &dst[s * 8]);
  }
}

// HL inner step (KSTEP=32): MI x NIv wave tile, 3-product split-bf16.
template <int MI, int NIv>
__device__ __forceinline__ void hl_step(const short* sA, const short* sB,
                                        int wm, int wn, int quad, int l15,
                                        f32x4 acc[MI][NIv]) {
  short8 a[MI], am[MI], b[NIv], bm[NIv];
#pragma unroll
  for (int mi = 0; mi < MI; ++mi) {
    const int rr = wm + mi * 16 + l15;
    a[mi] = *(const short8*)&sA[rr * 64 + ((quad ^ (rr & 7)) << 3)];
    am[mi] = *(const short8*)&sA[rr * 64 + (((quad + 4) ^ (rr & 7)) << 3)];
  }
#pragma unroll
  for (int ni = 0; ni < NIv; ++ni) {
    const int rr = wn + ni * 16 + l15;
    b[ni] = *(const short8*)&sB[rr * 64 + ((quad ^ (rr & 7)) << 3)];
    bm[ni] = *(const short8*)&sB[rr * 64 + (((quad + 4) ^ (rr & 7)) << 3)];
  }
#pragma unroll
  for (int mi = 0; mi < MI; ++mi)
#pragma unroll
    for (int ni = 0; ni < NIv; ++ni) {
      acc[mi][ni] = __builtin_amdgcn_mfma_f32_16x16x32_bf16(a[mi], b[ni],
                                                            acc[mi][ni], 0, 0, 0);
      acc[mi][ni] = __builtin_amdgcn_mfma_f32_16x16x32_bf16(a[mi], bm[ni],
                                                            acc[mi][ni], 0, 0, 0);
      acc[mi][ni] = __builtin_amdgcn_mfma_f32_16x16x32_bf16(am[mi], b[ni],
                                                            acc[mi][ni], 0, 0, 0);
    }
}

// non-HL inner step (KSTEP=64): two k=32 slices.
template <int MI, int NIv>
__device__ __forceinline__ void bf_step(const short* sA, const short* sB,
                                        int wm, int wn, int quad, int l15,
                                        f32x4 acc[MI][NIv]) {
#pragma unroll
  for (int s = 0; s < 2; ++s) {
    short8 a[MI], b[NIv];
#pragma unroll
    for (int mi = 0; mi < MI; ++mi) {
      const int rr = wm + mi * 16 + l15;
      a[mi] = *(const short8*)&sA[rr * 64 + (((s * 4 + quad) ^ (rr & 7)) << 3)];
    }
#pragma unroll
    for (int ni = 0; ni < NIv; ++ni) {
      const int rr = wn + ni * 16 + l15;
      b[ni] = *(const short8*)&sB[rr * 64 + (((s * 4 + quad) ^ (rr & 7)) << 3)];
    }
#pragma unroll
    for (int mi = 0; mi < MI; ++mi)
#pragma unroll
      for (int ni = 0; ni < NIv; ++ni)
        acc[mi][ni] = __builtin_amdgcn_mfma_f32_16x16x32_bf16(
            a[mi], b[ni], acc[mi][ni], 0, 0, 0);
  }
}

// ---------------------------------------------------------------------------
// qproj: q = x @ wqk, HL 3-product (q must be fp32-grade). R13: split-K x2,
// 1024 blocks x 256 thr, 128x64 tiles, uniform nk=16, 4 blocks/CU.
// R12 POST-MORTEM: fence/finisher reduction (device-scope __threadfence per
// block = L2 writeback/invalidate) poisoned all co-resident blocks' staging
// locality -> 290 us. R13 uses the PROVEN pv_gemm pattern instead: plain
// fp32 atomicAdd into qf (L2 hardware atomics, NO fences; exactly 2
// commutative contributions per element -> deterministic). qf zeroed in
// prep_all; q2bf materializes qh afterwards.
// ---------------------------------------------------------------------------
__global__ __launch_bounds__(256, 4)
void qproj(const short* __restrict__ xh, const short* __restrict__ xl,
           const short* __restrict__ wqkTh, const short* __restrict__ wqkTl,
           float* __restrict__ qf) {
  __shared__ short sA[128 * 64];
  __shared__ short sB[64 * 64];
  const int tid = threadIdx.x;
  const int w = tid >> 6, lane = tid & 63;
  const int quad = lane >> 4, l15 = lane & 15;
  const int wm = (w >> 1) * 64, wn = (w & 1) * 32;

  const int b = blockIdx.x;
  const int tile = b & 511;  // partners b and b+512 share a CU (heuristic)
  const int h = b >> 9;      // K-half
  const int mt = tile >> 4, nt = tile & 15;  // 32 x 16 tile grid
  const int m0 = mt * 128, n0 = nt * 64;
  const int kb = h * 512;

  f32x4 acc[4][2];
#pragma unroll
  for (int mi = 0; mi < 4; ++mi)
#pragma unroll
    for (int ni = 0; ni < 2; ++ni)
#pragma unroll
      for (int r = 0; r < 4; ++r) acc[mi][ni][r] = 0.f;

  for (int kt = 0; kt < 16; ++kt) {
    const int k0 = kb + kt * 32;
    stage_sw<128, true, 256>(xh, xl, 1024, m0, k0, sA, tid);
    stage_sw<64, true, 256>(wqkTh, wqkTl, 1024, n0, k0, sB, tid);
    __syncthreads();
    hl_step<4, 2>(sA, sB, wm, wn, quad, l15, acc);
    __syncthreads();
  }

#pragma unroll
  for (int mi = 0; mi < 4; ++mi)
#pragma unroll
    for (int ni = 0; ni < 2; ++ni)
#pragma unroll
      for (int r = 0; r < 4; ++r) {
        const int row = m0 + wm + mi * 16 + quad * 4 + r;
        const int col = n0 + wn + ni * 16 + l15;
        atomicAdd(&qf[(size_t)row * D_MODEL + col], acc[mi][ni][r]);
      }
}

// ---------------------------------------------------------------------------
// q2bf: qh = bf16(qf). 2048 blocks x 256 thr, 8 floats/thread (24 MB, ~5 us).
// ---------------------------------------------------------------------------
__global__ __launch_bounds__(256)
void q2bf(const float* __restrict__ qf, short* __restrict__ qh) {
  const int idx = blockIdx.x * 256 + threadIdx.x;
  const float4 a = ((const float4*)qf)[idx * 2];
  const float4 c = ((const float4*)qf)[idx * 2 + 1];
  short8 o;
  o[0] = f2bf(a.x); o[1] = f2bf(a.y); o[2] = f2bf(a.z); o[3] = f2bf(a.w);
  o[4] = f2bf(c.x); o[5] = f2bf(c.y); o[6] = f2bf(c.z); o[7] = f2bf(c.w);
  ((short8*)qh)[idx] = o;
}

// ---------------------------------------------------------------------------
// Fused QK + vT dispatch, 784 blocks x 256 thr (4 waves, 64x64 wave tiles):
//  blocks [0,528): S~ = qh @ xh^T causal (supertile-8, 1-PRODUCT bf16 —
//    estimate only, stored bf16; total error |s~-s| <~ 26 incl. quant,
//    refined exactly in softmax for entries within 64 of the row max)
//  blocks [528,784): vT = (x @ wov)^T rect NT GEMM (bf16, ldc 4096)
// All blocks ~equal length (16 K-iters) — uniform 3 blocks/CU.
// ---------------------------------------------------------------------------
__global__ __launch_bounds__(256, 2)
void fused_qk_v(const short* __restrict__ qh, const short* __restrict__ xh,
                const short* __restrict__ wovT, short* __restrict__ S,
                short* __restrict__ vT) {
  __shared__ short sA[128 * 64];
  __shared__ short sB[128 * 64];
  const int tid = threadIdx.x;
  const int w = tid >> 6, lane = tid & 63;
  const int quad = lane >> 4, l15 = lane & 15;
  const int wm = (w >> 1) * 64, wn = (w & 1) * 64;

  f32x4 acc[4][4];
#pragma unroll
  for (int mi = 0; mi < 4; ++mi)
#pragma unroll
    for (int ni = 0; ni < 4; ++ni)
#pragma unroll
      for (int r = 0; r < 4; ++r) acc[mi][ni][r] = 0.f;

  if (blockIdx.x < 528) {
    // ---- QK causal estimate, supertile-8 decode ----
    const int f = blockIdx.x;
    int R;
    if (f < 36) R = 0;
    else if (f < 136) R = 1;
    else if (f < 300) R = 2;
    else R = 3;
    const int rem = f - (32 * R * R + 4 * R);
    const int full = R << 6;
    int mt, nt;
    if (rem < full) {
      const int C = rem >> 6, ww = rem & 63;
      mt = 8 * R + (ww >> 3);
      nt = 8 * C + (ww & 7);
    } else {
      const int d = rem - full;
      int lm = 0;
      while ((lm + 1) * (lm + 2) / 2 <= d) ++lm;
      mt = 8 * R + lm;
      nt = 8 * R + d - lm * (lm + 1) / 2;
    }
    const int m0 = mt * 128, n0 = nt * 128;
    for (int kt = 0; kt < 16; ++kt) {
      const int k0 = kt * 64;
      stage_sw<128, false, 256>(qh, nullptr, 1024, m0, k0, sA, tid);
      stage_sw<128, false, 256>(xh, nullptr, 1024, n0, k0, sB, tid);
      __syncthreads();
      bf_step<4, 4>(sA, sB, wm, wn, quad, l15, acc);
      __syncthreads();
    }
#pragma unroll
    for (int mi = 0; mi < 4; ++mi)
#pragma unroll
      for (int ni = 0; ni < 4; ++ni)
#pragma unroll
        for (int r = 0; r < 4; ++r) {
          const int row = m0 + wm + mi * 16 + quad * 4 + r;
          const int col = n0 + wn + ni * 16 + l15;
          S[(size_t)row * N_SEQ + col] = f2bf(acc[mi][ni][r]);
        }
  } else {
    // ---- vT = (x @ wov)^T : C[m][n] = sum_d wovT[m][d] * xh[n][d] ----
    const int f2 = blockIdx.x - 528;
    const int mt = f2 >> 5, nt = f2 & 31;
    const int m0 = mt * 128, n0 = nt * 128;
    for (int kt = 0; kt < 16; ++kt) {
      const int k0 = kt * 64;
      stage_sw<128, false, 256>(wovT, nullptr, 1024, m0, k0, sA, tid);
      stage_sw<128, false, 256>(xh, nullptr, 1024, n0, k0, sB, tid);
      __syncthreads();
      bf_step<4, 4>(sA, sB, wm, wn, quad, l15, acc);
      __syncthreads();
    }
#pragma unroll
    for (int mi = 0; mi < 4; ++mi)
#pragma unroll
      for (int ni = 0; ni < 4; ++ni)
#pragma unroll
        for (int r = 0; r < 4; ++r) {
          const int row = m0 + wm + mi * 16 + quad * 4 + r;
          const int col = n0 + wn + ni * 16 + l15;
          vT[(size_t)row * N_SEQ + col] = f2bf(acc[mi][ni][r]);
        }
  }
}

// ---------------------------------------------------------------------------
// Softmax + sparse exact refinement, one block (256 thr) per row, in place.
// S~ bf16 (threshold 64 covers est+quant error ~26; unrefined true weight
// <= e^-12 — negligible). Row cache fv[2][8] statically indexed (rule #20).
// Candidates refined wave-parallel; exact fp32 q row read from qf.
// Exact row max = max(refv) since any unrefined entry < thr < best cand.
// ---------------------------------------------------------------------------
__global__ __launch_bounds__(256)
void softmax_refine(short* __restrict__ S, const float* __restrict__ qfg,
                    const short* __restrict__ xh, const short* __restrict__ xl) {
  const int gi = blockIdx.x;
  const int valid = gi + 1;
  const int padded = ((gi >> 7) + 1) << 7;
  const int nf8 = padded >> 3;
  short* srow = S + (size_t)gi * N_SEQ;
  const int tid = threadIdx.x;
  const int w = tid >> 6, lane = tid & 63;
  __shared__ float wred[4];
  __shared__ float sm, sil;
  __shared__ __align__(16) float qf[D_MODEL];
  __shared__ int cand[CAND_CAP];
  __shared__ float refv[CAND_CAP];
  __shared__ int ccnt;

  // load row (bf16 -> f32 regs, static layout) + estimate max
  float fv[2][8];
  float m = -1e30f;
#pragma unroll
  for (int k = 0; k < 2; ++k) {
    const int j8 = tid + (k << 8);
    if (j8 < nf8) {
      const short8 h = ((const short8*)srow)[j8];
#pragma unroll
      for (int e = 0; e < 8; ++e) {
        fv[k][e] = bf2f(h[e]);
        if ((j8 << 3) + e < valid) m = fmaxf(m, fv[k][e]);
      }
    }
  }
#pragma unroll
  for (int off = 32; off > 0; off >>= 1) m = fmaxf(m, __shfl_down(m, off));
  if (lane == 0) wred[w] = m;
  // exact fp32 q row -> LDS (one float4 per thread: D/4 == 256)
  {
    const float4 qv = ((const float4*)(qfg + (size_t)gi * D_MODEL))[tid];
    qf[tid * 4 + 0] = qv.x;
    qf[tid * 4 + 1] = qv.y;
    qf[tid * 4 + 2] = qv.z;
    qf[tid * 4 + 3] = qv.w;
  }
  if (tid == 0) ccnt = 0;
  __syncthreads();
  if (tid == 0) sm = fmaxf(fmaxf(wred[0], wred[1]), fmaxf(wred[2], wred[3]));
  __syncthreads();

  // collect candidates
  const float thr = sm - 64.0f;
#pragma unroll
  for (int k = 0; k < 2; ++k) {
    const int j8 = tid + (k << 8);
    if (j8 < nf8) {
#pragma unroll
      for (int e = 0; e < 8; ++e) {
        const int j = (j8 << 3) + e;
        if (j < valid && fv[k][e] > thr) {
          const int ix = atomicAdd(&ccnt, 1);
          if (ix < CAND_CAP) cand[ix] = j;
        }
      }
    }
  }
  __syncthreads();
  const int nc = min(ccnt, CAND_CAP);

  // exact fp32 dot per candidate — one wave per candidate, vectorized loads
  for (int c = w; c < nc; c += 4) {
    const int j = cand[c];
    const short4* xhr = (const short4*)(xh + (size_t)j * D_MODEL);
    const short4* xlr = (const short4*)(xl + (size_t)j * D_MODEL);
    float part = 0.f;
#pragma unroll
    for (int s = 0; s < 4; ++s) {
      const int d4 = lane + (s << 6);
      const short4 hx = xhr[d4];
      const short4 lx = xlr[d4];
      const float4 qv = *(const float4*)&qf[d4 << 2];
      part += qv.x * (bf2f(hx.x) + bf2f(lx.x));
      part += qv.y * (bf2f(hx.y) + bf2f(lx.y));
      part += qv.z * (bf2f(hx.z) + bf2f(lx.z));
      part += qv.w * (bf2f(hx.w) + bf2f(lx.w));
    }
#pragma unroll
    for (int off = 32; off > 0; off >>= 1) part += __shfl_down(part, off);
    if (lane == 0) refv[c] = part;
  }
  __syncthreads();

  // exact row max = max over refined candidates (unrefined < thr < this)
  m = -1e30f;
  for (int c = 0; c < nc; ++c) m = fmaxf(m, refv[c]);

  // patch register copies — static indexing, scan the candidate list
#pragma unroll
  for (int k = 0; k < 2; ++k) {
    const int j8 = tid + (k << 8);
    if (j8 < nf8) {
#pragma unroll
      for (int e = 0; e < 8; ++e) {
        const int j = (j8 << 3) + e;
        float x = fv[k][e];
        for (int c = 0; c < nc; ++c)
          if (cand[c] == j) x = refv[c];
        fv[k][e] = x;
      }
    }
  }

  // sum
  float l = 0.f;
#pragma unroll
  for (int k = 0; k < 2; ++k) {
    const int j8 = tid + (k << 8);
    if (j8 < nf8) {
#pragma unroll
      for (int e = 0; e < 8; ++e) {
        const float p = ((j8 << 3) + e < valid) ? __expf(fv[k][e] - m) : 0.f;
        fv[k][e] = p;
        l += p;
      }
    }
  }
#pragma unroll
  for (int off = 32; off > 0; off >>= 1) l += __shfl_down(l, off);
  if (lane == 0) wred[w] = l;
  __syncthreads();
  if (tid == 0) sil = 1.f / (wred[0] + wred[1] + wred[2] + wred[3]);
  __syncthreads();
  const float il = sil;

  // write P bf16 in place (padding cols [valid,padded) get exact 0)
#pragma unroll
  for (int k = 0; k < 2; ++k) {
    const int j8 = tid + (k << 8);
    if (j8 < nf8) {
      short8 o;
#pragma unroll
      for (int e = 0; e < 8; ++e) o[e] = f2bf(fv[k][e] * il);
      ((short8*)srow)[j8] = o;
    }
  }
}

// ---------------------------------------------------------------------------
// PV: out = P @ v. Split-K x2 — 1024 blocks x 256 thr (4 waves, 64x32 wave
// tiles), each block one half-K chunk of a 128x64 tile, nk = mt+1 <= 32.
// Rank map gives every CU chunk sizes {v,33-v,w,33-w} (exactly 66 steps/CU)
// all co-resident (24 KB LDS -> 4 blocks/CU) -> 4-way overlap hides per-step
// latency. Epilogue: fp32 atomicAdd (exactly 2 commutative contributions per
// element); out zeroed in prep_all. A = P (bf16, lda 4096), B = vT (ldb 4096).
// ---------------------------------------------------------------------------
__global__ __launch_bounds__(256, 4)
void pv_gemm(const short* __restrict__ P, const short* __restrict__ vT,
             float* __restrict__ out) {
  __shared__ short sA[128 * 64];
  __shared__ short sB[64 * 64];
  const int tid = threadIdx.x;
  const int w = tid >> 6, lane = tid & 63;
  const int quad = lane >> 4, l15 = lane & 15;
  const int wm = (w >> 1) * 64, wn = (w & 1) * 32;

  // CU c hosts blocks {c, c+256, c+512, c+768} -> ranks {c, 511-c, 512+c,
  // 1023-c} -> nk {v, 33-v, w, 33-w}.
  const int b = blockIdx.x;
  int rk;
  if (b < 256) rk = b;
  else if (b < 512) rk = 767 - b;
  else if (b < 768) rk = b;
  else rk = 1791 - b;
  const int mt = 31 - (rk >> 5);   // rank desc by chunk size
  const int nt = (rk >> 1) & 15;
  const int h = rk & 1;            // which K-half
  const int m0 = mt * 128, n0 = nt * 64;
  const int nk = mt + 1;           // K-steps in this half (K_total = 2*nk*64)
  const int kbase = h * nk * 64;

  f32x4 acc[4][2];
#pragma unroll
  for (int mi = 0; mi < 4; ++mi)
#pragma unroll
    for (int ni = 0; ni < 2; ++ni)
#pragma unroll
      for (int r = 0; r < 4; ++r) acc[mi][ni][r] = 0.f;

  for (int kt = 0; kt < nk; ++kt) {
    const int k0 = kbase + kt * 64;
    stage_sw<128, false, 256>(P, nullptr, 4096, m0, k0, sA, tid);
    stage_sw<64, false, 256>(vT, nullptr, N_SEQ, n0, k0, sB, tid);
    __syncthreads();
    bf_step<4, 2>(sA, sB, wm, wn, quad, l15, acc);
    __syncthreads();
  }
#pragma unroll
  for (int mi = 0; mi < 4; ++mi)
#pragma unroll
    for (int ni = 0; ni < 2; ++ni)
#pragma unroll
      for (int r = 0; r < 4; ++r) {
        const int row = m0 + wm + mi * 16 + quad * 4 + r;
        const int col = n0 + wn + ni * 16 + l15;
        atomicAdd(&out[(size_t)row * D_MODEL + col], acc[mi][ni][r]);
      }
}

// ---------------------------------------------------------------------------
// Fused prep, flat grid of 4608 x 256 thr:
//  b < 4096: x elementwise split -> xh, xl ; zero out + qf (both accumulate)
//  b < 4352: wqk 64x64 tile -> wqkTh, wqkTl (transposed, hi+lo)
//  else    : wov tile -> wovT (transposed)
// ---------------------------------------------------------------------------
__global__ __launch_bounds__(256)
void prep_all(const float* __restrict__ x, const float* __restrict__ wqk,
              const float* __restrict__ wov, short* __restrict__ xh,
              short* __restrict__ xl, short* __restrict__ wqkTh,
              short* __restrict__ wqkTl, short* __restrict__ wovT,
              float* __restrict__ outz, float* __restrict__ qfz) {
  __shared__ short Th[64][72];
  __shared__ short Tl[64][72];
  const int tid = threadIdx.x;
  const int b = blockIdx.x;

  if (b < 4096) {
    const int idx = b * 256 + tid;
    const float4 v = ((const float4*)x)[idx];
    const float f[4] = {v.x, v.y, v.z, v.w};
    short h[4], l[4];
#pragma unroll
    for (int i = 0; i < 4; ++i) {
      h[i] = f2bf(f[i]);
      l[i] = f2bf(f[i] - bf2f(h[i]));
    }
    ((short4*)xh)[idx] = make_short4(h[0], h[1], h[2], h[3]);
    ((short4*)xl)[idx] = make_short4(l[0], l[1], l[2], l[3]);
    // zero both f32 accumulators (same 4096x1024 geometry as x)
    ((float4*)outz)[idx] = make_float4(0.f, 0.f, 0.f, 0.f);
    ((float4*)qfz)[idx] = make_float4(0.f, 0.f, 0.f, 0.f);
    return;
  }

  const bool is_qk = (b < 4352);
  const int local = b - (is_qk ? 4096 : 4352);
  const float* in = is_qk ? wqk : wov;
  short* hiT = is_qk ? wqkTh : wovT;
  short* loT = is_qk ? wqkTl : nullptr;
  const int r0 = (local & 15) * 64, c0 = (local >> 4) * 64;

#pragma unroll
  for (int i = 0; i < 4; ++i) {
    const int rr = (tid >> 4) + i * 16;
    const int cc = (tid & 15) * 4;
    const float4 v = *(const float4*)&in[(size_t)(r0 + rr) * D_MODEL + c0 + cc];
    const float f[4] = {v.x, v.y, v.z, v.w};
#pragma unroll
    for (int j = 0; j < 4; ++j) {
      const short h = f2bf(f[j]);
      Th[rr][cc + j] = h;
      Tl[rr][cc + j] = is_qk ? f2bf(f[j] - bf2f(h)) : (short)0;
    }
  }
  __syncthreads();
#pragma unroll
  for (int i = 0; i < 2; ++i) {
    const int idx = tid + i * 256;
    const int oc = idx >> 3;
    const int ch = (idx & 7) * 8;
    float4 u;
    short* t = (short*)&u;
#pragma unroll
    for (int j = 0; j < 8; ++j) t[j] = Th[ch + j][oc];
    *(float4*)&hiT[(size_t)(c0 + oc) * D_MODEL + r0 + ch] = u;
    if (loT) {
#pragma unroll
      for (int j = 0; j < 8; ++j) t[j] = Tl[ch + j][oc];
      *(float4*)&loT[(size_t)(c0 + oc) * D_MODEL + r0 + ch] = u;
    }
  }
}

// ---------------------------------------------------------------------------
extern "C" void kernel_launch(void* const* d_in, const int* in_sizes, int n_in,
                              void* d_out, int out_size, void* d_ws,
                              size_t ws_size, hipStream_t stream) {
  (void)in_sizes; (void)n_in; (void)out_size; (void)ws_size;
  const float* x   = (const float*)d_in[0];
  const float* wqk = (const float*)d_in[1];
  const float* wov = (const float*)d_in[2];
  float* out = (float*)d_out;

  const size_t MB = 1ull << 20;
  char* p = (char*)d_ws;
  short* xh    = (short*)(p);             //  8 MB 4096x1024 bf16 hi
  short* xl    = (short*)(p + 8 * MB);    //  8 MB           bf16 lo
  short* wqkTh = (short*)(p + 16 * MB);   //  2 MB
  short* wqkTl = (short*)(p + 18 * MB);   //  2 MB
  short* wovT  = (short*)(p + 20 * MB);   //  2 MB
  short* qh    = (short*)(p + 22 * MB);   //  8 MB 4096x1024 bf16 q hi
  short* vT    = (short*)(p + 30 * MB);   //  8 MB 1024x4096: vT[d][s]=(x@wov)[s][d]
  short* S     = (short*)(p + 38 * MB);   // 32 MB 4096x4096 bf16 S~ (P aliases)
  float* qf    = (float*)(p + 70 * MB);   // 16 MB 4096x1024 f32 exact q (accum)
                                          // total 86 MB

  prep_all<<<4608, 256, 0, stream>>>(x, wqk, wov, xh, xl, wqkTh, wqkTl, wovT,
                                     out, qf);
  // q = x @ wqk  (split-bf16 3-product, split-K x2, atomic f32 accumulate)
  qproj<<<1024, 256, 0, stream>>>(xh, xl, wqkTh, wqkTl, qf);
  // qh = bf16(qf)
  q2bf<<<2048, 256, 0, stream>>>(qf, qh);
  // fused: S~ = qh @ xh^T causal 1-product estimate (bf16) + vT = (x@wov)^T
  fused_qk_v<<<784, 256, 0, stream>>>(qh, xh, wovT, S, vT);
  // softmax with sparse exact refinement (exact q from qf) -> P bf16 in place
  softmax_refine<<<N_SEQ, 256, 0, stream>>>(S, qf, xh, xl);
  // out += P @ v  (split-K x2, per-CU balanced, 4-way co-residency)
  pv_gemm<<<1024, 256, 0, stream>>>((const short*)S, vT, out);
}

// Round 5
// 200.137 us; speedup vs baseline: 2.2708x; 1.1414x over previous
//
#include <hip/hip_runtime.h>
#include <hip/hip_bf16.h>
#include <math.h>

#define N_SEQ 4096
#define D_MODEL 1024
#define CAND_CAP 512

typedef __attribute__((ext_vector_type(8))) short short8;
typedef __attribute__((ext_vector_type(4))) float f32x4;

__device__ __forceinline__ short f2bf(float f) {
  __hip_bfloat16 h = __float2bfloat16(f);
  return *reinterpret_cast<short*>(&h);
}
__device__ __forceinline__ float bf2f(short h) {
  return __uint_as_float(((unsigned)(unsigned short)h) << 16);
}

// async global->LDS, 16B per lane. LDS dest must be wave-uniform base + lane*16.
__device__ __forceinline__ void gload16(const short* g, short* l) {
  __builtin_amdgcn_global_load_lds(
      (const __attribute__((address_space(1))) void*)g,
      (__attribute__((address_space(3))) void*)l, 16, 0, 0);
}

// ---------------------------------------------------------------------------
// XOR-swizzled staging (NT thr): tile ROWS x 64 shorts. Slot s (16B):
// r = s>>3, c8 = (s&7)^(r&7) -> fragment ds_read_b128 hits all 32 banks
// (2-way, free — verified R4: conflicts 6.5e6 -> 0). HL: row = [hi 32 | lo 32].
// ---------------------------------------------------------------------------
template <int ROWS, bool HL, int NT>
__device__ __forceinline__ void stage_sw(const short* __restrict__ hi,
                                         const short* __restrict__ lo, int ld,
                                         int r0, int k0, short* dst, int tid) {
#pragma unroll
  for (int i = 0; i < ROWS * 8 / NT; ++i) {
    const int s = i * NT + tid;
    const int r = s >> 3;
    const int c8 = (s & 7) ^ (r & 7);
    const short* src;
    int col;
    if (HL) {
      src = (c8 < 4) ? hi : lo;
      col = (c8 & 3) * 8;
    } else {
      src = hi;
      col = c8 * 8;
    }
    gload16(&src[(size_t)(r0 + r) * ld + k0 + col], &dst[s * 8]);
  }
}

// HL inner step (KSTEP=32): MI x NIv wave tile, 3-product split-bf16.
template <int MI, int NIv>
__device__ __forceinline__ void hl_step(const short* sA, const short* sB,
                                        int wm, int wn, int quad, int l15,
                                        f32x4 acc[MI][NIv]) {
  short8 a[MI], am[MI], b[NIv], bm[NIv];
#pragma unroll
  for (int mi = 0; mi < MI; ++mi) {
    const int rr = wm + mi * 16 + l15;
    a[mi] = *(const short8*)&sA[rr * 64 + ((quad ^ (rr & 7)) << 3)];
    am[mi] = *(const short8*)&sA[rr * 64 + (((quad + 4) ^ (rr & 7)) << 3)];
  }
#pragma unroll
  for (int ni = 0; ni < NIv; ++ni) {
    const int rr = wn + ni * 16 + l15;
    b[ni] = *(const short8*)&sB[rr * 64 + ((quad ^ (rr & 7)) << 3)];
    bm[ni] = *(const short8*)&sB[rr * 64 + (((quad + 4) ^ (rr & 7)) << 3)];
  }
#pragma unroll
  for (int mi = 0; mi < MI; ++mi)
#pragma unroll
    for (int ni = 0; ni < NIv; ++ni) {
      acc[mi][ni] = __builtin_amdgcn_mfma_f32_16x16x32_bf16(a[mi], b[ni],
                                                            acc[mi][ni], 0, 0, 0);
      acc[mi][ni] = __builtin_amdgcn_mfma_f32_16x16x32_bf16(a[mi], bm[ni],
                                                            acc[mi][ni], 0, 0, 0);
      acc[mi][ni] = __builtin_amdgcn_mfma_f32_16x16x32_bf16(am[mi], b[ni],
                                                            acc[mi][ni], 0, 0, 0);
    }
}

// non-HL inner step (KSTEP=64): two k=32 slices.
template <int MI, int NIv>
__device__ __forceinline__ void bf_step(const short* sA, const short* sB,
                                        int wm, int wn, int quad, int l15,
                                        f32x4 acc[MI][NIv]) {
#pragma unroll
  for (int s = 0; s < 2; ++s) {
    short8 a[MI], b[NIv];
#pragma unroll
    for (int mi = 0; mi < MI; ++mi) {
      const int rr = wm + mi * 16 + l15;
      a[mi] = *(const short8*)&sA[rr * 64 + (((s * 4 + quad) ^ (rr & 7)) << 3)];
    }
#pragma unroll
    for (int ni = 0; ni < NIv; ++ni) {
      const int rr = wn + ni * 16 + l15;
      b[ni] = *(const short8*)&sB[rr * 64 + (((s * 4 + quad) ^ (rr & 7)) << 3)];
    }
#pragma unroll
    for (int mi = 0; mi < MI; ++mi)
#pragma unroll
      for (int ni = 0; ni < NIv; ++ni)
        acc[mi][ni] = __builtin_amdgcn_mfma_f32_16x16x32_bf16(
            a[mi], b[ni], acc[mi][ni], 0, 0, 0);
  }
}

// ---------------------------------------------------------------------------
// qproj_v: fused q-projection + vT. 768 blocks x 256 thr = EXACTLY 3/CU
// (round-robin: every CU gets 2 qproj + 1 vT block). R13 post-mortem: split-K
// atomics wrote through to HBM (32 MB WRITE + RMW fetches, colliding bursts
// from simultaneous partners) -> qproj 52 us. R14: co-residency comes from
// fusing the INDEPENDENT vT GEMM instead of splitting K — zero cross-block
// reduction, plain stores only.
//  blocks [0,512): q = x @ wqk, 128x64 tiles, 32 HL 3-product K-steps;
//    epilogue writes qh (bf16) + qf (f32 exact) — q2bf kernel eliminated.
//  blocks [512,768): vT = (x @ wov)^T, 128x128 tiles, 16 bf16 K-steps
//    (~2x work/step -> block lengths balanced with the 32-step qproj path).
// ---------------------------------------------------------------------------
__global__ __launch_bounds__(256, 3)
void qproj_v(const short* __restrict__ xh, const short* __restrict__ xl,
             const short* __restrict__ wqkTh, const short* __restrict__ wqkTl,
             const short* __restrict__ wovT, short* __restrict__ qh,
             float* __restrict__ qf, short* __restrict__ vT) {
  __shared__ short sA[128 * 64];
  __shared__ short sB[128 * 64];  // qproj path uses only the first 64*64
  const int tid = threadIdx.x;
  const int w = tid >> 6, lane = tid & 63;
  const int quad = lane >> 4, l15 = lane & 15;

  if (blockIdx.x < 512) {
    // ---- qproj: 128x64 tile, full K, HL 3-product ----
    const int wm = (w >> 1) * 64, wn = (w & 1) * 32;
    const int mt = blockIdx.x >> 4, nt = blockIdx.x & 15;  // 32 x 16 grid
    const int m0 = mt * 128, n0 = nt * 64;

    f32x4 acc[4][2];
#pragma unroll
    for (int mi = 0; mi < 4; ++mi)
#pragma unroll
      for (int ni = 0; ni < 2; ++ni)
#pragma unroll
        for (int r = 0; r < 4; ++r) acc[mi][ni][r] = 0.f;

    for (int kt = 0; kt < 32; ++kt) {
      const int k0 = kt * 32;
      stage_sw<128, true, 256>(xh, xl, 1024, m0, k0, sA, tid);
      stage_sw<64, true, 256>(wqkTh, wqkTl, 1024, n0, k0, sB, tid);
      __syncthreads();
      hl_step<4, 2>(sA, sB, wm, wn, quad, l15, acc);
      __syncthreads();
    }
#pragma unroll
    for (int mi = 0; mi < 4; ++mi)
#pragma unroll
      for (int ni = 0; ni < 2; ++ni)
#pragma unroll
        for (int r = 0; r < 4; ++r) {
          const int row = m0 + wm + mi * 16 + quad * 4 + r;
          const int col = n0 + wn + ni * 16 + l15;
          const float v = acc[mi][ni][r];
          qh[(size_t)row * D_MODEL + col] = f2bf(v);
          qf[(size_t)row * D_MODEL + col] = v;
        }
  } else {
    // ---- vT = (x @ wov)^T : C[m][n] = sum_d wovT[m][d] * xh[n][d] ----
    const int wm = (w >> 1) * 64, wn = (w & 1) * 64;
    const int f2 = blockIdx.x - 512;
    const int mt = f2 >> 5, nt = f2 & 31;
    const int m0 = mt * 128, n0 = nt * 128;

    f32x4 acc[4][4];
#pragma unroll
    for (int mi = 0; mi < 4; ++mi)
#pragma unroll
      for (int ni = 0; ni < 4; ++ni)
#pragma unroll
        for (int r = 0; r < 4; ++r) acc[mi][ni][r] = 0.f;

    for (int kt = 0; kt < 16; ++kt) {
      const int k0 = kt * 64;
      stage_sw<128, false, 256>(wovT, nullptr, 1024, m0, k0, sA, tid);
      stage_sw<128, false, 256>(xh, nullptr, 1024, n0, k0, sB, tid);
      __syncthreads();
      bf_step<4, 4>(sA, sB, wm, wn, quad, l15, acc);
      __syncthreads();
    }
#pragma unroll
    for (int mi = 0; mi < 4; ++mi)
#pragma unroll
      for (int ni = 0; ni < 4; ++ni)
#pragma unroll
        for (int r = 0; r < 4; ++r) {
          const int row = m0 + wm + mi * 16 + quad * 4 + r;
          const int col = n0 + wn + ni * 16 + l15;
          vT[(size_t)row * N_SEQ + col] = f2bf(acc[mi][ni][r]);
        }
  }
}

// ---------------------------------------------------------------------------
// qk_est: S~ = qh @ xh^T causal estimate, 528 blocks x 256 thr (supertile-8
// decode, 1-PRODUCT bf16, stored bf16; total error |s~-s| <~ 26 incl. quant,
// refined exactly in softmax for entries within 64 of the row max).
// ---------------------------------------------------------------------------
__global__ __launch_bounds__(256, 2)
void qk_est(const short* __restrict__ qh, const short* __restrict__ xh,
            short* __restrict__ S) {
  __shared__ short sA[128 * 64];
  __shared__ short sB[128 * 64];
  const int tid = threadIdx.x;
  const int w = tid >> 6, lane = tid & 63;
  const int quad = lane >> 4, l15 = lane & 15;
  const int wm = (w >> 1) * 64, wn = (w & 1) * 64;

  f32x4 acc[4][4];
#pragma unroll
  for (int mi = 0; mi < 4; ++mi)
#pragma unroll
    for (int ni = 0; ni < 4; ++ni)
#pragma unroll
      for (int r = 0; r < 4; ++r) acc[mi][ni][r] = 0.f;

  // supertile-8 decode
  const int f = blockIdx.x;
  int R;
  if (f < 36) R = 0;
  else if (f < 136) R = 1;
  else if (f < 300) R = 2;
  else R = 3;
  const int rem = f - (32 * R * R + 4 * R);
  const int full = R << 6;
  int mt, nt;
  if (rem < full) {
    const int C = rem >> 6, ww = rem & 63;
    mt = 8 * R + (ww >> 3);
    nt = 8 * C + (ww & 7);
  } else {
    const int d = rem - full;
    int lm = 0;
    while ((lm + 1) * (lm + 2) / 2 <= d) ++lm;
    mt = 8 * R + lm;
    nt = 8 * R + d - lm * (lm + 1) / 2;
  }
  const int m0 = mt * 128, n0 = nt * 128;
  for (int kt = 0; kt < 16; ++kt) {
    const int k0 = kt * 64;
    stage_sw<128, false, 256>(qh, nullptr, 1024, m0, k0, sA, tid);
    stage_sw<128, false, 256>(xh, nullptr, 1024, n0, k0, sB, tid);
    __syncthreads();
    bf_step<4, 4>(sA, sB, wm, wn, quad, l15, acc);
    __syncthreads();
  }
#pragma unroll
  for (int mi = 0; mi < 4; ++mi)
#pragma unroll
    for (int ni = 0; ni < 4; ++ni)
#pragma unroll
      for (int r = 0; r < 4; ++r) {
        const int row = m0 + wm + mi * 16 + quad * 4 + r;
        const int col = n0 + wn + ni * 16 + l15;
        S[(size_t)row * N_SEQ + col] = f2bf(acc[mi][ni][r]);
      }
}

// ---------------------------------------------------------------------------
// Softmax + sparse exact refinement, one block (256 thr) per row, in place.
// S~ bf16 (threshold 64 covers est+quant error ~26; unrefined true weight
// <= e^-12 — negligible). Row cache fv[2][8] statically indexed (rule #20).
// Candidates refined wave-parallel; exact fp32 q row read from qf.
// Exact row max = max(refv) since any unrefined entry < thr < best cand.
// ---------------------------------------------------------------------------
__global__ __launch_bounds__(256)
void softmax_refine(short* __restrict__ S, const float* __restrict__ qfg,
                    const short* __restrict__ xh, const short* __restrict__ xl) {
  const int gi = blockIdx.x;
  const int valid = gi + 1;
  const int padded = ((gi >> 7) + 1) << 7;
  const int nf8 = padded >> 3;
  short* srow = S + (size_t)gi * N_SEQ;
  const int tid = threadIdx.x;
  const int w = tid >> 6, lane = tid & 63;
  __shared__ float wred[4];
  __shared__ float sm, sil;
  __shared__ __align__(16) float qf[D_MODEL];
  __shared__ int cand[CAND_CAP];
  __shared__ float refv[CAND_CAP];
  __shared__ int ccnt;

  // load row (bf16 -> f32 regs, static layout) + estimate max
  float fv[2][8];
  float m = -1e30f;
#pragma unroll
  for (int k = 0; k < 2; ++k) {
    const int j8 = tid + (k << 8);
    if (j8 < nf8) {
      const short8 h = ((const short8*)srow)[j8];
#pragma unroll
      for (int e = 0; e < 8; ++e) {
        fv[k][e] = bf2f(h[e]);
        if ((j8 << 3) + e < valid) m = fmaxf(m, fv[k][e]);
      }
    }
  }
#pragma unroll
  for (int off = 32; off > 0; off >>= 1) m = fmaxf(m, __shfl_down(m, off));
  if (lane == 0) wred[w] = m;
  // exact fp32 q row -> LDS (one float4 per thread: D/4 == 256)
  {
    const float4 qv = ((const float4*)(qfg + (size_t)gi * D_MODEL))[tid];
    qf[tid * 4 + 0] = qv.x;
    qf[tid * 4 + 1] = qv.y;
    qf[tid * 4 + 2] = qv.z;
    qf[tid * 4 + 3] = qv.w;
  }
  if (tid == 0) ccnt = 0;
  __syncthreads();
  if (tid == 0) sm = fmaxf(fmaxf(wred[0], wred[1]), fmaxf(wred[2], wred[3]));
  __syncthreads();

  // collect candidates
  const float thr = sm - 64.0f;
#pragma unroll
  for (int k = 0; k < 2; ++k) {
    const int j8 = tid + (k << 8);
    if (j8 < nf8) {
#pragma unroll
      for (int e = 0; e < 8; ++e) {
        const int j = (j8 << 3) + e;
        if (j < valid && fv[k][e] > thr) {
          const int ix = atomicAdd(&ccnt, 1);
          if (ix < CAND_CAP) cand[ix] = j;
        }
      }
    }
  }
  __syncthreads();
  const int nc = min(ccnt, CAND_CAP);

  // exact fp32 dot per candidate — one wave per candidate, vectorized loads
  for (int c = w; c < nc; c += 4) {
    const int j = cand[c];
    const short4* xhr = (const short4*)(xh + (size_t)j * D_MODEL);
    const short4* xlr = (const short4*)(xl + (size_t)j * D_MODEL);
    float part = 0.f;
#pragma unroll
    for (int s = 0; s < 4; ++s) {
      const int d4 = lane + (s << 6);
      const short4 hx = xhr[d4];
      const short4 lx = xlr[d4];
      const float4 qv = *(const float4*)&qf[d4 << 2];
      part += qv.x * (bf2f(hx.x) + bf2f(lx.x));
      part += qv.y * (bf2f(hx.y) + bf2f(lx.y));
      part += qv.z * (bf2f(hx.z) + bf2f(lx.z));
      part += qv.w * (bf2f(hx.w) + bf2f(lx.w));
    }
#pragma unroll
    for (int off = 32; off > 0; off >>= 1) part += __shfl_down(part, off);
    if (lane == 0) refv[c] = part;
  }
  __syncthreads();

  // exact row max = max over refined candidates (unrefined < thr < this)
  m = -1e30f;
  for (int c = 0; c < nc; ++c) m = fmaxf(m, refv[c]);

  // patch register copies — static indexing, scan the candidate list
#pragma unroll
  for (int k = 0; k < 2; ++k) {
    const int j8 = tid + (k << 8);
    if (j8 < nf8) {
#pragma unroll
      for (int e = 0; e < 8; ++e) {
        const int j = (j8 << 3) + e;
        float x = fv[k][e];
        for (int c = 0; c < nc; ++c)
          if (cand[c] == j) x = refv[c];
        fv[k][e] = x;
      }
    }
  }

  // sum
  float l = 0.f;
#pragma unroll
  for (int k = 0; k < 2; ++k) {
    const int j8 = tid + (k << 8);
    if (j8 < nf8) {
#pragma unroll
      for (int e = 0; e < 8; ++e) {
        const float p = ((j8 << 3) + e < valid) ? __expf(fv[k][e] - m) : 0.f;
        fv[k][e] = p;
        l += p;
      }
    }
  }
#pragma unroll
  for (int off = 32; off > 0; off >>= 1) l += __shfl_down(l, off);
  if (lane == 0) wred[w] = l;
  __syncthreads();
  if (tid == 0) sil = 1.f / (wred[0] + wred[1] + wred[2] + wred[3]);
  __syncthreads();
  const float il = sil;

  // write P bf16 in place (padding cols [valid,padded) get exact 0)
#pragma unroll
  for (int k = 0; k < 2; ++k) {
    const int j8 = tid + (k << 8);
    if (j8 < nf8) {
      short8 o;
#pragma unroll
      for (int e = 0; e < 8; ++e) o[e] = f2bf(fv[k][e] * il);
      ((short8*)srow)[j8] = o;
    }
  }
}

// ---------------------------------------------------------------------------
// PV: out = P @ v. Split-K x2 — 1024 blocks x 256 thr (4 waves, 64x32 wave
// tiles), each block one half-K chunk of a 128x64 tile, nk = mt+1 <= 32.
// Rank map gives every CU chunk sizes {v,33-v,w,33-w} (exactly 66 steps/CU)
// all co-resident (24 KB LDS -> 4 blocks/CU) -> 4-way overlap hides per-step
// latency. Epilogue: fp32 atomicAdd (staggered partner finish times keep the
// 2nd RMW L2-warm — unlike R13's qproj); out zeroed in prep_all.
// A = P (bf16, lda 4096), B = vT (ldb 4096).
// ---------------------------------------------------------------------------
__global__ __launch_bounds__(256, 4)
void pv_gemm(const short* __restrict__ P, const short* __restrict__ vT,
             float* __restrict__ out) {
  __shared__ short sA[128 * 64];
  __shared__ short sB[64 * 64];
  const int tid = threadIdx.x;
  const int w = tid >> 6, lane = tid & 63;
  const int quad = lane >> 4, l15 = lane & 15;
  const int wm = (w >> 1) * 64, wn = (w & 1) * 32;

  // CU c hosts blocks {c, c+256, c+512, c+768} -> ranks {c, 511-c, 512+c,
  // 1023-c} -> nk {v, 33-v, w, 33-w}.
  const int b = blockIdx.x;
  int rk;
  if (b < 256) rk = b;
  else if (b < 512) rk = 767 - b;
  else if (b < 768) rk = b;
  else rk = 1791 - b;
  const int mt = 31 - (rk >> 5);   // rank desc by chunk size
  const int nt = (rk >> 1) & 15;
  const int h = rk & 1;            // which K-half
  const int m0 = mt * 128, n0 = nt * 64;
  const int nk = mt + 1;           // K-steps in this half (K_total = 2*nk*64)
  const int kbase = h * nk * 64;

  f32x4 acc[4][2];
#pragma unroll
  for (int mi = 0; mi < 4; ++mi)
#pragma unroll
    for (int ni = 0; ni < 2; ++ni)
#pragma unroll
      for (int r = 0; r < 4; ++r) acc[mi][ni][r] = 0.f;

  for (int kt = 0; kt < nk; ++kt) {
    const int k0 = kbase + kt * 64;
    stage_sw<128, false, 256>(P, nullptr, 4096, m0, k0, sA, tid);
    stage_sw<64, false, 256>(vT, nullptr, N_SEQ, n0, k0, sB, tid);
    __syncthreads();
    bf_step<4, 2>(sA, sB, wm, wn, quad, l15, acc);
    __syncthreads();
  }
#pragma unroll
  for (int mi = 0; mi < 4; ++mi)
#pragma unroll
    for (int ni = 0; ni < 2; ++ni)
#pragma unroll
      for (int r = 0; r < 4; ++r) {
        const int row = m0 + wm + mi * 16 + quad * 4 + r;
        const int col = n0 + wn + ni * 16 + l15;
        atomicAdd(&out[(size_t)row * D_MODEL + col], acc[mi][ni][r]);
      }
}

// ---------------------------------------------------------------------------
// Fused prep, flat grid of 4608 x 256 thr:
//  b < 4096: x elementwise split -> xh, xl ; zero out (pv accumulates)
//  b < 4352: wqk 64x64 tile -> wqkTh, wqkTl (transposed, hi+lo)
//  else    : wov tile -> wovT (transposed)
// ---------------------------------------------------------------------------
__global__ __launch_bounds__(256)
void prep_all(const float* __restrict__ x, const float* __restrict__ wqk,
              const float* __restrict__ wov, short* __restrict__ xh,
              short* __restrict__ xl, short* __restrict__ wqkTh,
              short* __restrict__ wqkTl, short* __restrict__ wovT,
              float* __restrict__ outz) {
  __shared__ short Th[64][72];
  __shared__ short Tl[64][72];
  const int tid = threadIdx.x;
  const int b = blockIdx.x;

  if (b < 4096) {
    const int idx = b * 256 + tid;
    const float4 v = ((const float4*)x)[idx];
    const float f[4] = {v.x, v.y, v.z, v.w};
    short h[4], l[4];
#pragma unroll
    for (int i = 0; i < 4; ++i) {
      h[i] = f2bf(f[i]);
      l[i] = f2bf(f[i] - bf2f(h[i]));
    }
    ((short4*)xh)[idx] = make_short4(h[0], h[1], h[2], h[3]);
    ((short4*)xl)[idx] = make_short4(l[0], l[1], l[2], l[3]);
    // zero the output accumulator (same 4096x1024 f32 geometry as x)
    ((float4*)outz)[idx] = make_float4(0.f, 0.f, 0.f, 0.f);
    return;
  }

  const bool is_qk = (b < 4352);
  const int local = b - (is_qk ? 4096 : 4352);
  const float* in = is_qk ? wqk : wov;
  short* hiT = is_qk ? wqkTh : wovT;
  short* loT = is_qk ? wqkTl : nullptr;
  const int r0 = (local & 15) * 64, c0 = (local >> 4) * 64;

#pragma unroll
  for (int i = 0; i < 4; ++i) {
    const int rr = (tid >> 4) + i * 16;
    const int cc = (tid & 15) * 4;
    const float4 v = *(const float4*)&in[(size_t)(r0 + rr) * D_MODEL + c0 + cc];
    const float f[4] = {v.x, v.y, v.z, v.w};
#pragma unroll
    for (int j = 0; j < 4; ++j) {
      const short h = f2bf(f[j]);
      Th[rr][cc + j] = h;
      Tl[rr][cc + j] = is_qk ? f2bf(f[j] - bf2f(h)) : (short)0;
    }
  }
  __syncthreads();
#pragma unroll
  for (int i = 0; i < 2; ++i) {
    const int idx = tid + i * 256;
    const int oc = idx >> 3;
    const int ch = (idx & 7) * 8;
    float4 u;
    short* t = (short*)&u;
#pragma unroll
    for (int j = 0; j < 8; ++j) t[j] = Th[ch + j][oc];
    *(float4*)&hiT[(size_t)(c0 + oc) * D_MODEL + r0 + ch] = u;
    if (loT) {
#pragma unroll
      for (int j = 0; j < 8; ++j) t[j] = Tl[ch + j][oc];
      *(float4*)&loT[(size_t)(c0 + oc) * D_MODEL + r0 + ch] = u;
    }
  }
}

// ---------------------------------------------------------------------------
extern "C" void kernel_launch(void* const* d_in, const int* in_sizes, int n_in,
                              void* d_out, int out_size, void* d_ws,
                              size_t ws_size, hipStream_t stream) {
  (void)in_sizes; (void)n_in; (void)out_size; (void)ws_size;
  const float* x   = (const float*)d_in[0];
  const float* wqk = (const float*)d_in[1];
  const float* wov = (const float*)d_in[2];
  float* out = (float*)d_out;

  const size_t MB = 1ull << 20;
  char* p = (char*)d_ws;
  short* xh    = (short*)(p);             //  8 MB 4096x1024 bf16 hi
  short* xl    = (short*)(p + 8 * MB);    //  8 MB           bf16 lo
  short* wqkTh = (short*)(p + 16 * MB);   //  2 MB
  short* wqkTl = (short*)(p + 18 * MB);   //  2 MB
  short* wovT  = (short*)(p + 20 * MB);   //  2 MB
  short* qh    = (short*)(p + 22 * MB);   //  8 MB 4096x1024 bf16 q hi
  short* vT    = (short*)(p + 30 * MB);   //  8 MB 1024x4096: vT[d][s]=(x@wov)[s][d]
  short* S     = (short*)(p + 38 * MB);   // 32 MB 4096x4096 bf16 S~ (P aliases)
  float* qf    = (float*)(p + 70 * MB);   // 16 MB 4096x1024 f32 exact q
                                          // total 86 MB

  prep_all<<<4608, 256, 0, stream>>>(x, wqk, wov, xh, xl, wqkTh, wqkTl, wovT,
                                     out);
  // fused: q = x @ wqk (HL 3-product, full-K, writes qh+qf) + vT = (x@wov)^T
  // 768 blocks = 3/CU, zero cross-block reduction
  qproj_v<<<768, 256, 0, stream>>>(xh, xl, wqkTh, wqkTl, wovT, qh, qf, vT);
  // S~ = qh @ xh^T causal 1-product estimate (bf16)
  qk_est<<<528, 256, 0, stream>>>(qh, xh, S);
  // softmax with sparse exact refinement (exact q from qf) -> P bf16 in place
  softmax_refine<<<N_SEQ, 256, 0, stream>>>(S, qf, xh, xl);
  // out += P @ v  (split-K x2, per-CU balanced, 4-way co-residency)
  pv_gemm<<<1024, 256, 0, stream>>>((const short*)S, vT, out);
}